// Round 5
// baseline (388.514 us; speedup 1.0000x reference)
//
#include <hip/hip_runtime.h>
#include <math.h>

#define NS 4096
#define NF 512
#define NB 16
#define NC 10
#define HSIZE 8192
#define HMASK 8191
#define HEMPTY 0xFFFFFFFFu
#define WS_XT_OFF 1024   // bytes reserved for counts at base of workspace

// ---------------- kernel 1 (fallback only): per-(b,c) class counts ----------------
__global__ void count_classes_kernel(const int* __restrict__ y, float* __restrict__ counts) {
    __shared__ int hist[NC];
    const int b = blockIdx.x;
    if (threadIdx.x < NC) hist[threadIdx.x] = 0;
    __syncthreads();
    for (int s = threadIdx.x; s < NS; s += blockDim.x)
        atomicAdd(&hist[y[b * NS + s]], 1);
    __syncthreads();
    if (threadIdx.x < NC) counts[b * NC + threadIdx.x] = (float)hist[threadIdx.x];
}

// ---------------- helpers ----------------
__device__ __forceinline__ float wave_reduce_add(float v) {
    #pragma unroll
    for (int off = 32; off > 0; off >>= 1) v += __shfl_down(v, off, 64);
    return v;
}
__device__ __forceinline__ float wave_reduce_max(float v) {
    #pragma unroll
    for (int off = 32; off > 0; off >>= 1) v = fmaxf(v, __shfl_down(v, off, 64));
    return v;
}

// ---------------- kernel T: tiled transpose X[b,s,f] -> XT[b,f,s] + class counts ---
// 64x64 tile per block, float4 on both sides, LDS [64][65] kills bank conflicts.
// The 16 blocks with (blockIdx.y==0 && blockIdx.z==0) also build counts[b][*]
// (absorbed into the transpose schedule -> removes a serial kernel launch).
__launch_bounds__(256)
__global__ void transpose_kernel(const float* __restrict__ X, float* __restrict__ XT,
                                 const int* __restrict__ y, float* __restrict__ counts) {
    __shared__ float t[64][65];
    __shared__ int hist[NC];
    const int b  = blockIdx.x;
    const int s0 = blockIdx.y * 64;
    const int f0 = blockIdx.z * 64;
    const int tid = threadIdx.x;

    const int fi = (tid & 15) * 4;     // 0..60
    const int si = tid >> 4;           // 0..15
    const float* Xb = X + ((size_t)b * NS + s0) * NF + f0;
    #pragma unroll
    for (int i = 0; i < 4; i++) {
        const int s = si + 16 * i;
        const float4 v = *(const float4*)(Xb + (size_t)s * NF + fi);
        t[s][fi + 0] = v.x; t[s][fi + 1] = v.y;
        t[s][fi + 2] = v.z; t[s][fi + 3] = v.w;
    }
    __syncthreads();

    const int sj = (tid & 15) * 4;
    const int fj = tid >> 4;
    float* XTb = XT + ((size_t)b * NF + f0) * NS + s0;
    #pragma unroll
    for (int i = 0; i < 4; i++) {
        const int f = fj + 16 * i;
        float4 v;
        v.x = t[sj + 0][f]; v.y = t[sj + 1][f];
        v.z = t[sj + 2][f]; v.w = t[sj + 3][f];
        *(float4*)(XTb + (size_t)f * NS + sj) = v;
    }

    if (blockIdx.y == 0 && blockIdx.z == 0) {      // block-uniform condition
        if (tid < NC) hist[tid] = 0;
        __syncthreads();
        const int4* yb = (const int4*)(y + (size_t)b * NS);
        #pragma unroll
        for (int i = 0; i < 4; i++) {              // 4096 ints = 1024 int4
            const int4 v = yb[i * 256 + tid];
            atomicAdd(&hist[v.x], 1); atomicAdd(&hist[v.y], 1);
            atomicAdd(&hist[v.z], 1); atomicAdd(&hist[v.w], 1);
        }
        __syncthreads();
        if (tid < NC) counts[b * NC + tid] = (float)hist[tid];
    }
}

// ---------------- fused kernel building blocks ----------------
__device__ __forceinline__ void prep_group(const float4 xf, const int4 yi,
    float& sum, float& sumsq, float& sumabs, float& maxabs, float& nancnt,
    float* csum, unsigned int* P, unsigned int* S)
{
    const float xe[4] = { xf.x, xf.y, xf.z, xf.w };
    const int   ye[4] = { yi.x, yi.y, yi.z, yi.w };
    #pragma unroll
    for (int j = 0; j < 4; j++) {
        float x = xe[j];
        if (x != x) { nancnt += 1.f; x = 0.f; }   // nan_to_num
        sum += x;
        sumsq = fmaf(x, x, sumsq);
        const float a = fabsf(x);
        sumabs += a;
        maxabs = fmaxf(maxabs, a);
        #pragma unroll
        for (int c = 0; c < NC; c++) csum[c] += (ye[j] == c) ? x : 0.f;
        unsigned int p = __float_as_uint(x);
        if (p == 0x80000000u) p = 0u;             // -0.0 == +0.0 value semantics
        P[j] = p;
        S[j] = (p * 2654435761u) >> 19;           // top 13 bits -> [0,8192)
    }
}

__device__ __forceinline__ void cas_batch(unsigned int* hash,
    const unsigned int* S, const unsigned int* P, unsigned int* O)
{
    #pragma unroll
    for (int j = 0; j < 4; j++)                    // 4 independent DS atomics,
        O[j] = atomicCAS(&hash[S[j]], HEMPTY, P[j]); // issued back-to-back
}

__device__ __forceinline__ void resolve_batch(unsigned int* hash,
    const unsigned int* S, const unsigned int* P, const unsigned int* O, float& uniq)
{
    #pragma unroll
    for (int j = 0; j < 4; j++) {
        const unsigned int o = O[j];
        if (o == HEMPTY) { uniq += 1.f; continue; }   // first insertion
        if (o == P[j]) continue;                       // duplicate
        unsigned int sl = S[j];
        for (;;) {                                     // rare: continue probing
            sl = (sl + 1) & HMASK;
            const unsigned int oo = atomicCAS(&hash[sl], HEMPTY, P[j]);
            if (oo == HEMPTY) { uniq += 1.f; break; }
            if (oo == P[j]) break;
        }
    }
}

// ---------------- kernel 2 (fast): fused stats + hash-unique + MLP on XT ----------
// one 256-thread workgroup per (b, f) column (contiguous in XT -> float4 loads).
// Software-pipelined: loads one group ahead (reg double-buffer); CAS batches
// ping-pong A/B so each batch's resolve overlaps the NEXT batch's DS latency
// and the next group's ~130 VALU prep ops.
// LDS = exactly 32 KB (reduction buffers aliased into hash after a barrier)
// -> 5 blocks/CU; launch_bounds(256,5) caps VGPR at 102.
__launch_bounds__(256, 5)
__global__ void fused_stats_mlp_xt(const float* __restrict__ XT,
                                   const int* __restrict__ y,
                                   const float* __restrict__ counts,
                                   const float* __restrict__ w1,
                                   const float* __restrict__ b1,
                                   const float* __restrict__ w2,
                                   const float* __restrict__ b2,
                                   float* __restrict__ out) {
    __shared__ __align__(16) unsigned int hash[HSIZE];   // 32 KB, multi-purpose

    const int w = blockIdx.x;
    const int g = (w & 7) * 1024 + (w >> 3);   // XCD swizzle, bijection over [0,8192)
    const int b = g >> 9;
    const int f = g & (NF - 1);
    const int tid = threadIdx.x;
    const int wave = tid >> 6, lane = tid & 63;

    // vectorized hash init: 8x ds_write_b128
    uint4* h4 = (uint4*)hash;
    const uint4 e4 = make_uint4(HEMPTY, HEMPTY, HEMPTY, HEMPTY);
    #pragma unroll
    for (int i = 0; i < HSIZE / 4 / 256; i++) h4[i * 256 + tid] = e4;
    __syncthreads();

    const float4* Xc4 = (const float4*)(XT + ((size_t)b * NF + f) * NS);
    const int4*   yp4 = (const int4*)(y + (size_t)b * NS);

    float sum = 0.f, sumsq = 0.f, sumabs = 0.f, maxabs = 0.f, nancnt = 0.f, uniq = 0.f;
    float csum[NC];
    #pragma unroll
    for (int c = 0; c < NC; c++) csum[c] = 0.f;

    unsigned int PA[4], SA[4], OA[4], PB[4], SB[4], OB[4];

    // -------- software-pipelined 4-group loop (fully unrolled, static regs) ------
    float4 xc = Xc4[tid];              int4 yc = yp4[tid];
    float4 xn = Xc4[256 + tid];        int4 yn = yp4[256 + tid];

    // group 0
    prep_group(xc, yc, sum, sumsq, sumabs, maxabs, nancnt, csum, PA, SA);
    cas_batch(hash, SA, PA, OA);
    xc = xn; yc = yn;
    xn = Xc4[512 + tid]; yn = yp4[512 + tid];
    // group 1 (prep+CAS B overlaps CAS A latency; then resolve A)
    prep_group(xc, yc, sum, sumsq, sumabs, maxabs, nancnt, csum, PB, SB);
    cas_batch(hash, SB, PB, OB);
    resolve_batch(hash, SA, PA, OA, uniq);
    xc = xn; yc = yn;
    xn = Xc4[768 + tid]; yn = yp4[768 + tid];
    // group 2
    prep_group(xc, yc, sum, sumsq, sumabs, maxabs, nancnt, csum, PA, SA);
    cas_batch(hash, SA, PA, OA);
    resolve_batch(hash, SB, PB, OB, uniq);
    xc = xn; yc = yn;
    // group 3
    prep_group(xc, yc, sum, sumsq, sumabs, maxabs, nancnt, csum, PB, SB);
    cas_batch(hash, SB, PB, OB);
    resolve_batch(hash, SA, PA, OA, uniq);
    resolve_batch(hash, SB, PB, OB, uniq);

    __syncthreads();   // ALL hash CAS complete before re-aliasing the region

    // -------- block reduction + final stats (aliased into hash region) ----------
    float (*red)[16] = (float(*)[16])hash;     // floats [0,64)
    float* stats_s   = (float*)hash + 64;      // floats [64,70)
    float* h_s       = (float*)hash + 128;     // floats [128,192)

    sum    = wave_reduce_add(sum);
    sumsq  = wave_reduce_add(sumsq);
    sumabs = wave_reduce_add(sumabs);
    nancnt = wave_reduce_add(nancnt);
    uniq   = wave_reduce_add(uniq);
    maxabs = wave_reduce_max(maxabs);
    #pragma unroll
    for (int c = 0; c < NC; c++) csum[c] = wave_reduce_add(csum[c]);

    if (lane == 0) {
        red[wave][0] = sum;    red[wave][1] = sumsq; red[wave][2] = sumabs;
        red[wave][3] = nancnt; red[wave][4] = uniq;  red[wave][5] = maxabs;
        #pragma unroll
        for (int c = 0; c < NC; c++) red[wave][6 + c] = csum[c];
    }
    __syncthreads();

    if (tid == 0) {
        float t[16];
        #pragma unroll
        for (int v = 0; v < 16; v++) t[v] = red[0][v];
        #pragma unroll
        for (int wv = 1; wv < 4; wv++) {
            #pragma unroll
            for (int v = 0; v < 16; v++) {
                if (v == 5) t[v] = fmaxf(t[v], red[wv][v]);
                else        t[v] += red[wv][v];
            }
        }
        const float invS = 1.f / (float)NS;
        const float gmean    = t[0] * invS;
        const float variance = fmaxf(t[1] * invS - gmean * gmean, 0.f);  // biased
        const float mean_abs = t[2] * invS;
        const float missing  = t[3] * invS;
        const float n_unique = t[4];
        const float max_abs  = t[5];
        float between = 0.f;
        #pragma unroll
        for (int c = 0; c < NC; c++) {
            const float cnt = counts[b * NC + c];
            const float cm  = t[6 + c] / fmaxf(cnt, 1.f);
            const float d   = cm - gmean;
            between += cnt * d * d;
        }
        between *= invS;                                   // counts.sum() == NS
        const float target = between / fmaxf(variance, 1e-6f);
        float st[6] = { target, missing, n_unique * invS, variance, mean_abs, max_abs };
        #pragma unroll
        for (int i = 0; i < 6; i++) {
            float v = st[i];
            if (!(fabsf(v) < INFINITY)) v = 0.f;           // nan_to_num
            stats_s[i] = v;
        }
    }
    __syncthreads();

    // MLP epilogue: 6 -> 64 (exact GELU) -> 128
    if (tid < 64) {
        float z = b1[tid];
        #pragma unroll
        for (int i = 0; i < 6; i++) z = fmaf(stats_s[i], w1[i * 64 + tid], z);
        h_s[tid] = 0.5f * z * (1.f + erff(z * 0.70710678118654752440f));
    }
    __syncthreads();
    if (tid < 128) {
        float o = b2[tid];
        #pragma unroll
        for (int j = 0; j < 64; j++) o = fmaf(h_s[j], w2[j * 128 + tid], o);
        out[(size_t)g * 128 + tid] = o;
    }
}

// ---------------- kernel 2 (fallback): round-0 strided version ----------------
__launch_bounds__(256)
__global__ void fused_stats_mlp_kernel(const float* __restrict__ X,
                                       const int* __restrict__ y,
                                       const float* __restrict__ counts,
                                       const float* __restrict__ w1,
                                       const float* __restrict__ b1,
                                       const float* __restrict__ w2,
                                       const float* __restrict__ b2,
                                       float* __restrict__ out) {
    __shared__ unsigned int hash[HSIZE];
    __shared__ float red[4][16];
    __shared__ float stats_s[6];
    __shared__ float h_s[64];

    const int w = blockIdx.x;
    const int g = (w & 7) * 1024 + (w >> 3);
    const int b = g >> 9;
    const int f = g & (NF - 1);
    const int tid = threadIdx.x;

    #pragma unroll
    for (int i = 0; i < HSIZE / 256; i++) hash[tid + i * 256] = HEMPTY;
    __syncthreads();

    const float* Xp = X + (size_t)b * NS * NF + f;
    const int*   yp = y + b * NS;

    float sum = 0.f, sumsq = 0.f, sumabs = 0.f, maxabs = 0.f, nancnt = 0.f, uniq = 0.f;
    float csum[NC];
    #pragma unroll
    for (int c = 0; c < NC; c++) csum[c] = 0.f;

    #pragma unroll
    for (int k0 = 0; k0 < 16; k0 += 8) {
        float xv[8]; int yv[8];
        #pragma unroll
        for (int k = 0; k < 8; k++) {
            const int s = (k0 + k) * 256 + tid;
            xv[k] = Xp[(size_t)s * NF];
            yv[k] = yp[s];
        }
        #pragma unroll
        for (int k = 0; k < 8; k++) {
            float x = xv[k];
            if (x != x) { nancnt += 1.f; x = 0.f; }
            sum += x;
            sumsq = fmaf(x, x, sumsq);
            const float a = fabsf(x);
            sumabs += a;
            maxabs = fmaxf(maxabs, a);
            const int yc = yv[k];
            #pragma unroll
            for (int c = 0; c < NC; c++) csum[c] += (yc == c) ? x : 0.f;
            unsigned int pat = __float_as_uint(x);
            if (pat == 0x80000000u) pat = 0u;
            unsigned int slot = (pat * 2654435761u) >> 19;
            for (;;) {
                const unsigned int old = atomicCAS(&hash[slot], HEMPTY, pat);
                if (old == HEMPTY) { uniq += 1.f; break; }
                if (old == pat) break;
                slot = (slot + 1) & HMASK;
            }
        }
    }

    sum    = wave_reduce_add(sum);
    sumsq  = wave_reduce_add(sumsq);
    sumabs = wave_reduce_add(sumabs);
    nancnt = wave_reduce_add(nancnt);
    uniq   = wave_reduce_add(uniq);
    maxabs = wave_reduce_max(maxabs);
    #pragma unroll
    for (int c = 0; c < NC; c++) csum[c] = wave_reduce_add(csum[c]);

    const int wave = tid >> 6, lane = tid & 63;
    if (lane == 0) {
        red[wave][0] = sum;    red[wave][1] = sumsq; red[wave][2] = sumabs;
        red[wave][3] = nancnt; red[wave][4] = uniq;  red[wave][5] = maxabs;
        #pragma unroll
        for (int c = 0; c < NC; c++) red[wave][6 + c] = csum[c];
    }
    __syncthreads();

    if (tid == 0) {
        float t[16];
        #pragma unroll
        for (int v = 0; v < 16; v++) t[v] = red[0][v];
        #pragma unroll
        for (int wv = 1; wv < 4; wv++) {
            #pragma unroll
            for (int v = 0; v < 16; v++) {
                if (v == 5) t[v] = fmaxf(t[v], red[wv][v]);
                else        t[v] += red[wv][v];
            }
        }
        const float invS = 1.f / (float)NS;
        const float gmean    = t[0] * invS;
        const float variance = fmaxf(t[1] * invS - gmean * gmean, 0.f);
        const float mean_abs = t[2] * invS;
        const float missing  = t[3] * invS;
        const float n_unique = t[4];
        const float max_abs  = t[5];
        float between = 0.f;
        #pragma unroll
        for (int c = 0; c < NC; c++) {
            const float cnt = counts[b * NC + c];
            const float cm  = t[6 + c] / fmaxf(cnt, 1.f);
            const float d   = cm - gmean;
            between += cnt * d * d;
        }
        between *= invS;
        const float target = between / fmaxf(variance, 1e-6f);
        float st[6] = { target, missing, n_unique * invS, variance, mean_abs, max_abs };
        #pragma unroll
        for (int i = 0; i < 6; i++) {
            float v = st[i];
            if (!(fabsf(v) < INFINITY)) v = 0.f;
            stats_s[i] = v;
        }
    }
    __syncthreads();

    if (tid < 64) {
        float z = b1[tid];
        #pragma unroll
        for (int i = 0; i < 6; i++) z = fmaf(stats_s[i], w1[i * 64 + tid], z);
        h_s[tid] = 0.5f * z * (1.f + erff(z * 0.70710678118654752440f));
    }
    __syncthreads();
    if (tid < 128) {
        float o = b2[tid];
        #pragma unroll
        for (int j = 0; j < 64; j++) o = fmaf(h_s[j], w2[j * 128 + tid], o);
        out[(size_t)g * 128 + tid] = o;
    }
}

extern "C" void kernel_launch(void* const* d_in, const int* in_sizes, int n_in,
                              void* d_out, int out_size, void* d_ws, size_t ws_size,
                              hipStream_t stream) {
    const float* X  = (const float*)d_in[0];
    const int*   y  = (const int*)d_in[1];
    const float* w1 = (const float*)d_in[2];
    const float* b1 = (const float*)d_in[3];
    const float* w2 = (const float*)d_in[4];
    const float* b2 = (const float*)d_in[5];
    float* out    = (float*)d_out;
    float* counts = (float*)d_ws;          // 16*10 floats at workspace base

    const size_t xt_bytes = (size_t)NB * NF * NS * sizeof(float);   // 128 MB
    if (ws_size >= xt_bytes + WS_XT_OFF) {
        float* XT = (float*)((char*)d_ws + WS_XT_OFF);
        transpose_kernel<<<dim3(NB, NS / 64, NF / 64), 256, 0, stream>>>(X, XT, y, counts);
        fused_stats_mlp_xt<<<NB * NF, 256, 0, stream>>>(XT, y, counts, w1, b1, w2, b2, out);
    } else {
        // workspace too small: proven strided path (round-0 structure)
        count_classes_kernel<<<NB, 256, 0, stream>>>(y, counts);
        fused_stats_mlp_kernel<<<NB * NF, 256, 0, stream>>>(X, y, counts, w1, b1, w2, b2, out);
    }
}